// Round 1
// baseline (178.823 us; speedup 1.0000x reference)
//
#include <hip/hip_runtime.h>
#include <math.h>

#define B 8
#define C 64
#define HIN 224
#define WIN 224
#define PLANE (HIN*WIN)        // 50176
#define PLANE4 (PLANE/4)       // 12544
#define QUART (PLANE4/4)       // 3136
#define OH 64
#define OW 128
#define OUT_PER_BC (OH*OW)     // 8192
#define NGRID (OH*OW)          // grid points per batch in the "small" corner
#define POOLED_SIZE (B*C*OH*OW) // 4194304

// ws layout (floats):
// [0, 2048)            : partial sums [bc][quarter]
// [2048, 2064)         : weight [8][2]
// [4096, 4096+131072)  : coords [b][8192] float2 (ix, iy)  -> 540 KB total
#define WS_PARTIAL 0
#define WS_WEIGHT 2048
#define WS_COORDS 4096

#define PI_F 3.14159265358979323846f

// ---------------- K1: global average pool partial sums ----------------
__global__ __launch_bounds__(256) void k1_gap(const float* __restrict__ x,
                                              float* __restrict__ ws) {
    int blk = blockIdx.x;          // bc*4 + q
    int bc  = blk >> 2, q = blk & 3;
    const float4* p = (const float4*)x + (size_t)bc * PLANE4 + q * QUART;
    int tid = threadIdx.x;
    float s = 0.f;
#pragma unroll
    for (int k = 0; k < 12; ++k) {
        float4 v = p[tid + k * 256];
        s += (v.x + v.y) + (v.z + v.w);
    }
    if (tid < QUART - 12 * 256) {  // remainder: 64 float4s
        float4 v = p[tid + 12 * 256];
        s += (v.x + v.y) + (v.z + v.w);
    }
    // wave (64-lane) reduce, then cross-wave via LDS
    for (int off = 32; off; off >>= 1) s += __shfl_down(s, off, 64);
    __shared__ float lds[4];
    if ((tid & 63) == 0) lds[tid >> 6] = s;
    __syncthreads();
    if (tid == 0) ws[WS_PARTIAL + blk] = lds[0] + lds[1] + lds[2] + lds[3];
}

// ---------------- K2: tiny MLP -> weight[8][2] ----------------
__global__ __launch_bounds__(256) void k2_mlp(const float* __restrict__ w1,
                                              const float* __restrict__ b1,
                                              const float* __restrict__ w2,
                                              const float* __restrict__ b2,
                                              float* __restrict__ ws,
                                              float* __restrict__ out_weight) {
    __shared__ float branch[B * C];    // 512
    __shared__ float hidden[B * 32];   // 256
    int tid = threadIdx.x;
    for (int i = tid; i < B * C; i += 256) {
        const float* pp = ws + WS_PARTIAL + i * 4;
        branch[i] = (pp[0] + pp[1] + pp[2] + pp[3]) * (1.0f / PLANE);
    }
    __syncthreads();
    {
        int b = tid >> 5, m = tid & 31;
        float h = b1[m];
        for (int c = 0; c < C; ++c) h += branch[b * C + c] * w1[c * 32 + m];
        hidden[b * 32 + m] = h > 0.f ? h : 0.f;
    }
    __syncthreads();
    if (tid < 16) {
        int bb = tid >> 1, k = tid & 1;
        float s = b2[k];
        for (int mm = 0; mm < 32; ++mm) s += hidden[bb * 32 + mm] * w2[mm * 2 + k];
        float wv = 1.f / (1.f + expf(-s));
        ws[WS_WEIGHT + tid] = wv;
        out_weight[tid] = wv;
    }
}

// ---------------- K2b: per-batch sampling coordinate table ----------------
__global__ __launch_bounds__(256) void k2b_coords(const float* __restrict__ wgt,
                                                  const float* __restrict__ l_t,
                                                  float2* __restrict__ coords) {
    int p = blockIdx.x * 256 + threadIdx.x;   // [0, 65536)
    int b = p >> 13;
    int rem = p & 8191;
    int i = rem >> 7;     // row (H dim), 0..63
    int j = rem & 127;    // col (W dim), 0..127
    float w0 = wgt[b * 2 + 0];
    float w1v = wgt[b * 2 + 1];
    float lo = logf(w0 * 0.01f);           // log(weight0 * R_MIN)
    float hi = logf(w1v * 0.6f);           // log(weight1 * R_MAX)
    float xg = (float)(i - 32) * (1.f / 32.f);
    float yg = (float)(j - 64) * (1.f / 64.f);
    float rr = sqrtf(xg * xg + yg * yg);
    float logr = logf(fmaxf(rr, 1e-12f));
    float r = 64.f * (logr - lo) / (hi - lo);
    float a = atan2f(yg, xg);
    if (!(a > 0.f)) a = 2.f * PI_F + a;
    float t = 0.5f * a * 64.f / PI_F;
    float gx = t * (1.f / 32.f) - 1.f + l_t[b * 2 + 0];
    float gy = r * (1.f / 32.f) - 1.f + l_t[b * 2 + 1];
    float ix = ((gx + 1.f) * (float)WIN - 1.f) * 0.5f;
    float iy = ((gy + 1.f) * (float)HIN - 1.f) * 0.5f;
    ix = fminf(fmaxf(ix, 0.f), (float)(WIN - 1));
    iy = fminf(fmaxf(iy, 0.f), (float)(HIN - 1));
    coords[p] = make_float2(ix, iy);
}

// ---------------- K3: bilinear sample + 4x4 avg pool ----------------
__device__ __forceinline__ float bilinear(const float* __restrict__ p,
                                          float ix, float iy) {
    float x0f = floorf(ix), y0f = floorf(iy);
    int x0 = (int)x0f, y0 = (int)y0f;
    float wx = ix - x0f, wy = iy - y0f;
    int x1 = min(x0 + 1, WIN - 1);
    int y1 = min(y0 + 1, HIN - 1);
    const float* r0 = p + y0 * WIN;
    const float* r1 = p + y1 * WIN;
    float v00 = r0[x0], v01 = r0[x1], v10 = r1[x0], v11 = r1[x1];
    float v0 = v00 + (v01 - v00) * wx;
    float v1 = v10 + (v11 - v10) * wx;
    return v0 + (v1 - v0) * wy;
}

__global__ __launch_bounds__(256) void k3_sample(const float* __restrict__ x,
                                                 const float* __restrict__ l_t,
                                                 const float2* __restrict__ coords,
                                                 float* __restrict__ out) {
    int bc = blockIdx.x;          // 0..511, = b*64 + c
    int b = bc >> 6;
    int tid = threadIdx.x;
    const float* plane = x + (size_t)bc * PLANE;
    float* o = out + (size_t)bc * OUT_PER_BC;

    // Constant-region sample: grid == (0,0) + l_t_prev[b] everywhere outside
    // the top-left 64x128 corner -> after 4x4 pooling, all outputs with
    // h>=16 or w>=32 equal ONE bilinear sample.
    float gx = l_t[b * 2 + 0], gy = l_t[b * 2 + 1];
    float ixc = fminf(fmaxf(((gx + 1.f) * (float)WIN - 1.f) * 0.5f, 0.f), (float)(WIN - 1));
    float iyc = fminf(fmaxf(((gy + 1.f) * (float)HIN - 1.f) * 0.5f, 0.f), (float)(HIN - 1));
    float vconst = bilinear(plane, ixc, iyc);

    // Fill constant region (coalesced; skip interesting corner)
#pragma unroll
    for (int k = 0; k < 32; ++k) {
        int oi = tid + k * 256;       // 0..8191
        int h = oi >> 7, w = oi & 127;
        if (!(h < 16 && w < 32)) o[oi] = vconst;
    }

    // Interesting corner: 16x32 outputs, each = mean of 16 bilinear samples
    const float2* cb = coords + b * NGRID;
#pragma unroll
    for (int rr = 0; rr < 2; ++rr) {
        int oi = tid + rr * 256;      // 0..511
        int h = oi >> 5, w = oi & 31;
        float acc = 0.f;
#pragma unroll
        for (int di = 0; di < 4; ++di) {
            const float2* cr = cb + (4 * h + di) * 128 + 4 * w;
#pragma unroll
            for (int dj = 0; dj < 4; ++dj) {
                float2 cxy = cr[dj];
                acc += bilinear(plane, cxy.x, cxy.y);
            }
        }
        o[h * 128 + w] = acc * (1.f / 16.f);
    }
}

extern "C" void kernel_launch(void* const* d_in, const int* in_sizes, int n_in,
                              void* d_out, int out_size, void* d_ws, size_t ws_size,
                              hipStream_t stream) {
    const float* x   = (const float*)d_in[0];
    const float* l_t = (const float*)d_in[1];
    const float* w1  = (const float*)d_in[2];
    const float* b1  = (const float*)d_in[3];
    const float* w2  = (const float*)d_in[4];
    const float* b2  = (const float*)d_in[5];
    float* out = (float*)d_out;
    float* ws  = (float*)d_ws;

    k1_gap<<<dim3(B * C * 4), dim3(256), 0, stream>>>(x, ws);
    k2_mlp<<<dim3(1), dim3(256), 0, stream>>>(w1, b1, w2, b2, ws, out + POOLED_SIZE);
    k2b_coords<<<dim3(NGRID * B / 256), dim3(256), 0, stream>>>(ws + WS_WEIGHT, l_t,
                                                                (float2*)(ws + WS_COORDS));
    k3_sample<<<dim3(B * C), dim3(256), 0, stream>>>(x, l_t,
                                                     (const float2*)(ws + WS_COORDS), out);
}